// Round 5
// baseline (21588.245 us; speedup 1.0000x reference)
//
#include <hip/hip_runtime.h>
#include <hip/hip_bf16.h>
#include <math.h>

typedef __hip_bfloat16 bf16;
typedef __attribute__((ext_vector_type(8))) short bf16x8;
typedef __attribute__((ext_vector_type(4))) float f32x4;

static constexpr int B_ = 8, C_ = 128, H_ = 128, W_ = 128;
static constexpr int N_ = H_ * W_;          // 16384
static constexpr int NWIN = 648;            // B * 9 * 9

__device__ __forceinline__ float b2f(bf16 v) { return __bfloat162float(v); }
__device__ __forceinline__ bf16 f2b(float v) { return __float2bfloat16(v); }
__device__ __forceinline__ float gelu_f(float x) {
    return 0.5f * x * (1.0f + erff(x * 0.70710678118654752f));
}

// ---------------- K1: 2x2 avg pool (fp32) ----------------
__global__ __launch_bounds__(256) void k_pool(const float* __restrict__ x, float* __restrict__ low) {
    int idx = blockIdx.x * 256 + threadIdx.x;       // 4,194,304
    int j = idx & 63, i = (idx >> 6) & 63, bc = idx >> 12;
    const float* p = x + (size_t)bc * N_ + (i * 2) * W_ + j * 2;
    low[idx] = (p[0] + p[1] + p[W_] + p[W_ + 1]) * 0.25f;
}

// ---------------- K2: hf = x - bilinear_up(low)  (bf16 out) ----------------
__global__ __launch_bounds__(256) void k_hf(const float* __restrict__ x, const float* __restrict__ low,
                                            bf16* __restrict__ hf) {
    int idx = blockIdx.x * 256 + threadIdx.x;       // 16,777,216
    int w = idx & 127, h = (idx >> 7) & 127, bc = idx >> 14;
    int jh = h >> 1, jw = w >> 1;
    int h0, h1; float wh0, wh1;
    if (h & 1) { h0 = jh; h1 = jh + 1 > 63 ? 63 : jh + 1; wh0 = 0.75f; wh1 = 0.25f; }
    else       { h0 = jh - 1 < 0 ? 0 : jh - 1; h1 = jh;   wh0 = 0.25f; wh1 = 0.75f; }
    int w0, w1; float ww0, ww1;
    if (w & 1) { w0 = jw; w1 = jw + 1 > 63 ? 63 : jw + 1; ww0 = 0.75f; ww1 = 0.25f; }
    else       { w0 = jw - 1 < 0 ? 0 : jw - 1; w1 = jw;   ww0 = 0.25f; ww1 = 0.75f; }
    const float* lp = low + (size_t)bc * 4096;
    float up = wh0 * (ww0 * lp[h0 * 64 + w0] + ww1 * lp[h0 * 64 + w1])
             + wh1 * (ww0 * lp[h1 * 64 + w0] + ww1 * lp[h1 * 64 + w1]);
    hf[idx] = f2b(x[idx] - up);
}

// ---------------- K3: sgate (fp32 out) ----------------
__global__ __launch_bounds__(256) void k_sgate(const bf16* __restrict__ hf, const float* __restrict__ gw,
                                               const float* __restrict__ gb, float* __restrict__ sg) {
    int idx = blockIdx.x * 256 + threadIdx.x;       // 131072
    int n = idx & (N_ - 1); int b = idx >> 14;
    const bf16* p = hf + (size_t)b * C_ * N_ + n;
    float s = 0.f;
    for (int c = 0; c < C_; ++c) s += gw[c] * fabsf(b2f(p[(size_t)c * N_]));
    s += gb[0];
    sg[idx] = 1.0f / (1.0f + expf(-s));
}

// ---------------- K4: g = gelu(dwconv3x3 dil2) (bf16) ----------------
__global__ __launch_bounds__(256) void k_dw3(const bf16* __restrict__ hf, const float* __restrict__ wdw,
                                             bf16* __restrict__ g) {
    int idx = blockIdx.x * 256 + threadIdx.x;
    int w = idx & 127, h = (idx >> 7) & 127, bc = idx >> 14, c = bc & 127;
    const bf16* p = hf + (size_t)bc * N_;
    const float* kw = wdw + c * 9;
    float s = 0.f;
    #pragma unroll
    for (int ky = 0; ky < 3; ++ky) {
        int hh = h + (ky - 1) * 2;
        if ((unsigned)hh >= 128u) continue;
        #pragma unroll
        for (int kx = 0; kx < 3; ++kx) {
            int ww = w + (kx - 1) * 2;
            if ((unsigned)ww >= 128u) continue;
            s += kw[ky * 3 + kx] * b2f(p[hh * W_ + ww]);
        }
    }
    g[idx] = f2b(gelu_f(s));
}

// ---------------- K5: pw GEMM + LTH epilogue -> x1 (bf16) ----------------
__global__ __launch_bounds__(256) void k_pw(const bf16* __restrict__ g, const float* __restrict__ pww,
                                            const float* __restrict__ pwb, const float* __restrict__ x,
                                            const float* __restrict__ scale, const float* __restrict__ sg,
                                            bf16* __restrict__ x1) {
    __shared__ __align__(16) float a_lds[128][64];
    __shared__ __align__(16) float w_lds[16][128];
    int tid = threadIdx.x;
    int gtok = blockIdx.x * 64; int b = gtok >> 14; int nb = gtok & (N_ - 1);
    const bf16* A = g + (size_t)b * C_ * N_ + nb;
    for (int e = tid; e < 8192; e += 256) { int c = e >> 6, i = e & 63; a_lds[c][i] = b2f(A[(size_t)c * N_ + i]); }
    int tn = tid & 15, to = tid >> 4;
    float acc[4][8] = {};
    for (int c0 = 0; c0 < 128; c0 += 16) {
        __syncthreads();
        for (int e = tid; e < 2048; e += 256) { int cc = e & 15, o = e >> 4; w_lds[cc][o] = pww[o * 128 + c0 + cc]; }
        __syncthreads();
        for (int cc = 0; cc < 16; ++cc) {
            float4 a4 = *(const float4*)&a_lds[c0 + cc][tn * 4];
            const float4* wr4 = (const float4*)&w_lds[cc][to * 8];
            float4 wa = wr4[0], wb = wr4[1];
            float wv[8] = {wa.x, wa.y, wa.z, wa.w, wb.x, wb.y, wb.z, wb.w};
            #pragma unroll
            for (int oj = 0; oj < 8; ++oj) {
                float wvv = wv[oj];
                acc[0][oj] += a4.x * wvv; acc[1][oj] += a4.y * wvv;
                acc[2][oj] += a4.z * wvv; acc[3][oj] += a4.w * wvv;
            }
        }
    }
    #pragma unroll
    for (int rr = 0; rr < 4; ++rr) {
        int n = nb + tn * 4 + rr;
        float sgv = sg[(b << 14) + n];
        #pragma unroll
        for (int oj = 0; oj < 8; ++oj) {
            int o = to * 8 + oj;
            size_t oaddr = (size_t)(b * C_ + o) * N_ + n;
            x1[oaddr] = f2b(x[oaddr] + scale[o] * (acc[rr][oj] + pwb[o]) * sgv);
        }
    }
}

// ---------------- K6: fused LN1 + qkv GEMM -> q,k [tok][c], v [c][tok] (bf16) ----------------
__global__ __launch_bounds__(256) void k_qkv(const bf16* __restrict__ x1, const float* __restrict__ lng,
                                             const float* __restrict__ lnb, const float* __restrict__ qkvw,
                                             bf16* __restrict__ q, bf16* __restrict__ k, bf16* __restrict__ v) {
    __shared__ __align__(16) float y_lds[128][64];
    __shared__ __align__(16) float w_lds[16][128];
    __shared__ float red2[8][64];
    __shared__ float mu_l[64], rs_l[64];
    int tid = threadIdx.x;
    int win = blockIdx.x >> 2; int tokbase = (blockIdx.x & 3) * 64;
    int b = win / 81; int r0 = win % 81; int top = (r0 / 9) * 14, left = (r0 % 9) * 14;
    for (int e = tid; e < 8192; e += 256) {
        int c = e >> 6, i = e & 63; int tok = tokbase + i; int p = tok >> 4, qq = tok & 15;
        y_lds[c][i] = b2f(x1[(size_t)(b * C_ + c) * N_ + (top + p) * W_ + (left + qq)]);
    }
    __syncthreads();
    { // LN stats: 4 partials per token
        int i = tid & 63, r = tid >> 6;
        float s = 0.f, ss = 0.f;
        for (int cc = r * 32; cc < r * 32 + 32; ++cc) { float vv = y_lds[cc][i]; s += vv; ss += vv * vv; }
        red2[r][i] = s; red2[4 + r][i] = ss;
    }
    __syncthreads();
    if (tid < 64) {
        float s = red2[0][tid] + red2[1][tid] + red2[2][tid] + red2[3][tid];
        float ss = red2[4][tid] + red2[5][tid] + red2[6][tid] + red2[7][tid];
        float mu = s * (1.f / 128.f); float var = ss * (1.f / 128.f) - mu * mu;
        mu_l[tid] = mu; rs_l[tid] = rsqrtf(var + 1e-6f);
    }
    __syncthreads();
    for (int e = tid; e < 8192; e += 256) {
        int c = e >> 6, i = e & 63;
        y_lds[c][i] = (y_lds[c][i] - mu_l[i]) * rs_l[i] * lng[c] + lnb[c];
    }
    int tn = tid & 15, to = tid >> 4;
    for (int pass = 0; pass < 3; ++pass) {
        float acc[4][8] = {};
        for (int c0 = 0; c0 < 128; c0 += 16) {
            __syncthreads();
            for (int e = tid; e < 2048; e += 256) { int cc = e >> 7, o = e & 127; w_lds[cc][o] = qkvw[(c0 + cc) * 384 + pass * 128 + o]; }
            __syncthreads();
            for (int cc = 0; cc < 16; ++cc) {
                float4 a4 = *(const float4*)&y_lds[c0 + cc][tn * 4];
                const float4* wr4 = (const float4*)&w_lds[cc][to * 8];
                float4 wa = wr4[0], wb = wr4[1];
                float wv[8] = {wa.x, wa.y, wa.z, wa.w, wb.x, wb.y, wb.z, wb.w};
                #pragma unroll
                for (int oj = 0; oj < 8; ++oj) {
                    float wvv = wv[oj];
                    acc[0][oj] += a4.x * wvv; acc[1][oj] += a4.y * wvv;
                    acc[2][oj] += a4.z * wvv; acc[3][oj] += a4.w * wvv;
                }
            }
        }
        if (pass < 2) {
            bf16* outp = (pass == 0) ? q : k;      // [win][tok][c]
            #pragma unroll
            for (int rr = 0; rr < 4; ++rr) {
                int tok = tokbase + tn * 4 + rr;
                union { bf16 h[8]; uint4 u; } tmp;
                #pragma unroll
                for (int oj = 0; oj < 8; ++oj) tmp.h[oj] = f2b(acc[rr][oj]);
                *(uint4*)(outp + ((size_t)win * 256 + tok) * 128 + to * 8) = tmp.u;
            }
        } else {                                    // v: [win][c][tok]
            #pragma unroll
            for (int rr = 0; rr < 4; ++rr) {
                int tok = tokbase + tn * 4 + rr;
                #pragma unroll
                for (int oj = 0; oj < 8; ++oj)
                    v[(size_t)win * 32768 + (size_t)(to * 8 + oj) * 256 + tok] = f2b(acc[rr][oj]);
            }
        }
        __syncthreads();
    }
}

// ---------------- K7: MFMA attention core: softmax(QK^T*scale)V -> o [win][tok][c] ----------------
__global__ __launch_bounds__(256) void k_attn_mfma(const bf16* __restrict__ qb, const bf16* __restrict__ kb,
                                                   const bf16* __restrict__ vb, bf16* __restrict__ ob) {
    __shared__ __align__(16) char lds[49152];   // [0,32K): q (16K) then P (32K); [32K,48K): K/V chunk
    int tid = threadIdx.x;
    int lane = tid & 63, w = tid >> 6;
    int l15 = lane & 15, lhi = lane >> 4;
    int win = blockIdx.x >> 2, qbase = (blockIdx.x & 3) * 64;
    const bf16* qg = qb + ((size_t)win * 256 + qbase) * 128;   // [64][128]
    const bf16* kg = kb + (size_t)win * 256 * 128;             // [256][128]
    const bf16* vg = vb + (size_t)win * 128 * 256;             // [128][256]
    char* chunk = lds + 32768;
    for (int e = tid; e < 1024; e += 256) {
        int row = e >> 4, slot = e & 15;
        uint4 val = *(const uint4*)((const char*)qg + row * 256 + slot * 16);
        *(uint4*)(lds + row * 256 + ((slot * 16) ^ ((row & 7) << 4))) = val;
    }
    __syncthreads();
    bf16x8 afr[4];
    {
        int row = w * 16 + l15;
        #pragma unroll
        for (int cc = 0; cc < 4; ++cc) {
            int cb = cc * 64 + lhi * 16;
            afr[cc] = *(const bf16x8*)(lds + row * 256 + (cb ^ ((row & 7) << 4)));
        }
    }
    f32x4 acc[16];
    #pragma unroll
    for (int t = 0; t < 16; ++t) acc[t] = (f32x4){0.f, 0.f, 0.f, 0.f};
    for (int kc = 0; kc < 4; ++kc) {
        __syncthreads();
        for (int e = tid; e < 1024; e += 256) {
            int row = e >> 4, slot = e & 15;
            uint4 val = *(const uint4*)((const char*)kg + (size_t)(kc * 64 + row) * 256 + slot * 16);
            *(uint4*)(chunk + row * 256 + ((slot * 16) ^ ((row & 7) << 4))) = val;
        }
        __syncthreads();
        #pragma unroll
        for (int t = 0; t < 4; ++t) {
            int row = t * 16 + l15;
            #pragma unroll
            for (int cc = 0; cc < 4; ++cc) {
                int cb = cc * 64 + lhi * 16;
                bf16x8 bfr = *(const bf16x8*)(chunk + row * 256 + (cb ^ ((row & 7) << 4)));
                acc[kc * 4 + t] = __builtin_amdgcn_mfma_f32_16x16x32_bf16(afr[cc], bfr, acc[kc * 4 + t], 0, 0, 0);
            }
        }
    }
    const float sm_scale = 0.08838834764831845f;   // 128^-0.5
    #pragma unroll
    for (int r = 0; r < 4; ++r) {
        float m = -1e30f;
        #pragma unroll
        for (int t = 0; t < 16; ++t) m = fmaxf(m, acc[t][r]);
        #pragma unroll
        for (int d2 = 1; d2 < 16; d2 <<= 1) m = fmaxf(m, __shfl_xor(m, d2, 64));
        float ssum = 0.f;
        #pragma unroll
        for (int t = 0; t < 16; ++t) { float p = __expf((acc[t][r] - m) * sm_scale); acc[t][r] = p; ssum += p; }
        #pragma unroll
        for (int d2 = 1; d2 < 16; d2 <<= 1) ssum += __shfl_xor(ssum, d2, 64);
        float inv = 1.f / ssum;
        #pragma unroll
        for (int t = 0; t < 16; ++t) acc[t][r] *= inv;
    }
    #pragma unroll
    for (int t = 0; t < 16; ++t) {
        #pragma unroll
        for (int r = 0; r < 4; ++r) {
            int row = w * 16 + lhi * 4 + r;
            int cb = (t * 16 + l15) * 2;
            *(bf16*)(lds + row * 512 + (cb ^ ((row & 7) << 4))) = f2b(acc[t][r]);
        }
    }
    f32x4 oacc[8];
    #pragma unroll
    for (int t = 0; t < 8; ++t) oacc[t] = (f32x4){0.f, 0.f, 0.f, 0.f};
    for (int vc = 0; vc < 4; ++vc) {
        __syncthreads();
        for (int e = tid; e < 1024; e += 256) {
            int row = e >> 3, slot = e & 7;
            uint4 val = *(const uint4*)((const char*)vg + (size_t)row * 512 + vc * 128 + slot * 16);
            *(uint4*)(chunk + row * 128 + ((slot * 16) ^ ((row & 7) << 4))) = val;
        }
        __syncthreads();
        #pragma unroll
        for (int jc = 0; jc < 2; ++jc) {
            int prow = w * 16 + l15;
            int pcb = vc * 128 + jc * 64 + lhi * 16;
            bf16x8 ap = *(const bf16x8*)(lds + prow * 512 + (pcb ^ ((prow & 7) << 4)));
            #pragma unroll
            for (int ct = 0; ct < 8; ++ct) {
                int vrow = ct * 16 + l15;
                int vcb = jc * 64 + lhi * 16;
                bf16x8 bv = *(const bf16x8*)(chunk + vrow * 128 + (vcb ^ ((vrow & 7) << 4)));
                oacc[ct] = __builtin_amdgcn_mfma_f32_16x16x32_bf16(ap, bv, oacc[ct], 0, 0, 0);
            }
        }
    }
    bf16* og = ob + ((size_t)win * 256 + qbase) * 128;
    #pragma unroll
    for (int ct = 0; ct < 8; ++ct) {
        #pragma unroll
        for (int r = 0; r < 4; ++r) {
            int row = w * 16 + lhi * 4 + r;
            og[row * 128 + ct * 16 + l15] = f2b(oacc[ct][r]);
        }
    }
}

// ---------------- K8a: LN1 + gate GEMM + gelu -> z [win][c][tok] (bf16) ----------------
__global__ __launch_bounds__(256) void k_zgate(const bf16* __restrict__ x1, const float* __restrict__ lng,
                                               const float* __restrict__ lnb, const float* __restrict__ gatew,
                                               const float* __restrict__ gateb, bf16* __restrict__ z) {
    __shared__ __align__(16) float y_lds[128][64];
    __shared__ __align__(16) float w_lds[16][128];
    __shared__ float red2[8][64];
    __shared__ float mu_l[64], rs_l[64];
    int tid = threadIdx.x;
    int win = blockIdx.x >> 2; int tokbase = (blockIdx.x & 3) * 64;
    int b = win / 81; int r0 = win % 81; int top = (r0 / 9) * 14, left = (r0 % 9) * 14;
    for (int e = tid; e < 8192; e += 256) {
        int c = e >> 6, i = e & 63; int tok = tokbase + i; int p = tok >> 4, qq = tok & 15;
        y_lds[c][i] = b2f(x1[(size_t)(b * C_ + c) * N_ + (top + p) * W_ + (left + qq)]);
    }
    __syncthreads();
    {
        int i = tid & 63, r = tid >> 6;
        float s = 0.f, ss = 0.f;
        for (int cc = r * 32; cc < r * 32 + 32; ++cc) { float vv = y_lds[cc][i]; s += vv; ss += vv * vv; }
        red2[r][i] = s; red2[4 + r][i] = ss;
    }
    __syncthreads();
    if (tid < 64) {
        float s = red2[0][tid] + red2[1][tid] + red2[2][tid] + red2[3][tid];
        float ss = red2[4][tid] + red2[5][tid] + red2[6][tid] + red2[7][tid];
        float mu = s * (1.f / 128.f); float var = ss * (1.f / 128.f) - mu * mu;
        mu_l[tid] = mu; rs_l[tid] = rsqrtf(var + 1e-6f);
    }
    __syncthreads();
    for (int e = tid; e < 8192; e += 256) {
        int c = e >> 6, i = e & 63;
        y_lds[c][i] = (y_lds[c][i] - mu_l[i]) * rs_l[i] * lng[c] + lnb[c];
    }
    int tn = tid & 15, to = tid >> 4;
    float acc[4][8] = {};
    for (int c0 = 0; c0 < 128; c0 += 16) {
        __syncthreads();
        for (int e = tid; e < 2048; e += 256) { int cc = e >> 7, o = e & 127; w_lds[cc][o] = gatew[(c0 + cc) * 128 + o]; }
        __syncthreads();
        for (int cc = 0; cc < 16; ++cc) {
            float4 a4 = *(const float4*)&y_lds[c0 + cc][tn * 4];
            const float4* wr4 = (const float4*)&w_lds[cc][to * 8];
            float4 wa = wr4[0], wb = wr4[1];
            float wv[8] = {wa.x, wa.y, wa.z, wa.w, wb.x, wb.y, wb.z, wb.w};
            #pragma unroll
            for (int oj = 0; oj < 8; ++oj) {
                float wvv = wv[oj];
                acc[0][oj] += a4.x * wvv; acc[1][oj] += a4.y * wvv;
                acc[2][oj] += a4.z * wvv; acc[3][oj] += a4.w * wvv;
            }
        }
    }
    #pragma unroll
    for (int rr = 0; rr < 4; ++rr) {
        int tok = tokbase + tn * 4 + rr;
        #pragma unroll
        for (int oj = 0; oj < 8; ++oj) {
            int o = to * 8 + oj;
            z[(size_t)win * 32768 + (size_t)o * 256 + tok] = f2b(gelu_f(acc[rr][oj] + gateb[o]));
        }
    }
}

// ---------------- K8b: PE + gate-mul + proj GEMM + crop residual -> t2 [win][c][tok] (bf16) ----------------
__global__ __launch_bounds__(256) void k_pe_proj(const bf16* __restrict__ ob, const bf16* __restrict__ qb,
                                                 const bf16* __restrict__ zb, const bf16* __restrict__ x1,
                                                 const float* __restrict__ pew, const float* __restrict__ peb,
                                                 const float* __restrict__ projw, bf16* __restrict__ t2) {
    __shared__ __align__(16) float y_lds[128][64];     // gated A for proj
    __shared__ __align__(16) float w_lds[16][128];
    __shared__ __align__(16) bf16 xt_lds[128][64];     // raw crop (residual)
    int tid = threadIdx.x;
    int win = blockIdx.x >> 2; int qbase = (blockIdx.x & 3) * 64;
    int b = win / 81; int r0 = win % 81; int top = (r0 / 9) * 14, left = (r0 % 9) * 14;
    for (int e = tid; e < 8192; e += 256) {
        int c = e >> 6, i = e & 63; int tok = qbase + i; int p = tok >> 4, qq = tok & 15;
        xt_lds[c][i] = x1[(size_t)(b * C_ + c) * N_ + (top + p) * W_ + (left + qq)];
    }
    // ---- PE + gate -> y_lds[c][tok], 4 sub-phases x 8 channels/thread ----
    {
        int tok = tid & 63, cg = tid >> 6;
        int gtok = qbase + tok; int pp = gtok >> 4, qq = gtok & 15;
        #pragma unroll 1
        for (int sub = 0; sub < 4; ++sub) {
            int cb = cg * 8 + sub * 32;
            float pv[8];
            #pragma unroll
            for (int cc = 0; cc < 8; ++cc) pv[cc] = peb[cb + cc];
            #pragma unroll
            for (int ky = 0; ky < 3; ++ky) {
                int py = pp + ky - 1; if ((unsigned)py >= 16u) continue;
                #pragma unroll
                for (int kx = 0; kx < 3; ++kx) {
                    int qx = qq + kx - 1; if ((unsigned)qx >= 16u) continue;
                    union { uint4 u; bf16 h[8]; } qu;
                    qu.u = *(const uint4*)(qb + ((size_t)win * 256 + py * 16 + qx) * 128 + cb);
                    #pragma unroll
                    for (int cc = 0; cc < 8; ++cc)
                        pv[cc] += pew[(cb + cc) * 9 + ky * 3 + kx] * b2f(qu.h[cc]);
                }
            }
            union { uint4 u; bf16 h[8]; } ou;
            ou.u = *(const uint4*)(ob + ((size_t)win * 256 + gtok) * 128 + cb);
            #pragma unroll
            for (int cc = 0; cc < 8; ++cc) {
                int c = cb + cc;
                float zval = b2f(zb[(size_t)win * 32768 + (size_t)c * 256 + gtok]);
                y_lds[c][tok] = (b2f(ou.h[cc]) + pv[cc]) * zval;
            }
        }
    }
    int tn = tid & 15, to = tid >> 4;
    // ---- proj GEMM + crop residual -> t2 ----
    float pacc[4][8] = {};
    for (int c0 = 0; c0 < 128; c0 += 16) {
        __syncthreads();
        for (int e = tid; e < 2048; e += 256) { int cc = e >> 7, o = e & 127; w_lds[cc][o] = projw[(c0 + cc) * 128 + o]; }
        __syncthreads();
        for (int cc = 0; cc < 16; ++cc) {
            float4 a4 = *(const float4*)&y_lds[c0 + cc][tn * 4];
            const float4* wr4 = (const float4*)&w_lds[cc][to * 8];
            float4 wa = wr4[0], wb = wr4[1];
            float wv[8] = {wa.x, wa.y, wa.z, wa.w, wb.x, wb.y, wb.z, wb.w};
            #pragma unroll
            for (int oj = 0; oj < 8; ++oj) {
                float wvv = wv[oj];
                pacc[0][oj] += a4.x * wvv; pacc[1][oj] += a4.y * wvv;
                pacc[2][oj] += a4.z * wvv; pacc[3][oj] += a4.w * wvv;
            }
        }
    }
    #pragma unroll
    for (int rr = 0; rr < 4; ++rr) {
        int tok = qbase + tn * 4 + rr;
        #pragma unroll
        for (int oj = 0; oj < 8; ++oj) {
            int o = to * 8 + oj;
            t2[(size_t)win * 32768 + (size_t)o * 256 + tok] = f2b(pacc[rr][oj] + b2f(xt_lds[o][tn * 4 + rr]));
        }
    }
}

// ---------------- K9: overlap-fold with divisor -> x2 (bf16) ----------------
__global__ __launch_bounds__(256) void k_fold(const bf16* __restrict__ t2, bf16* __restrict__ x2) {
    int idx = blockIdx.x * 256 + threadIdx.x;      // 16,777,216
    int w = idx & 127, h = (idx >> 7) & 127, c = (idx >> 14) & 127, b = idx >> 21;
    int imin = (h < 16) ? 0 : (h - 2) / 14; int imax = h / 14; if (imax > 8) imax = 8;
    int jmin = (w < 16) ? 0 : (w - 2) / 14; int jmax = w / 14; if (jmax > 8) jmax = 8;
    float sum = 0.f;
    for (int i = imin; i <= imax; ++i)
        for (int j = jmin; j <= jmax; ++j) {
            int win = (b * 9 + i) * 9 + j;
            sum += b2f(t2[(size_t)win * 32768 + c * 256 + (h - i * 14) * 16 + (w - j * 14)]);
        }
    int cnt = (imax - imin + 1) * (jmax - jmin + 1);
    x2[idx] = f2b(sum / (float)cnt);
}

// ---------------- K10: LN2 -> xn (bf16) ----------------
__global__ __launch_bounds__(256) void k_ln2(const bf16* __restrict__ x2, const float* __restrict__ gam,
                                             const float* __restrict__ bet, bf16* __restrict__ xn) {
    int idx = blockIdx.x * 256 + threadIdx.x;      // 131072
    int n = idx & (N_ - 1); int b = idx >> 14;
    const bf16* p = x2 + (size_t)b * C_ * N_ + n;
    float s = 0.f, ss = 0.f;
    for (int c = 0; c < C_; ++c) { float v = b2f(p[(size_t)c * N_]); s += v; ss += v * v; }
    float mu = s * (1.f / 128.f);
    float var = ss * (1.f / 128.f) - mu * mu;
    float rs = rsqrtf(var + 1e-6f);
    bf16* o = xn + (size_t)b * C_ * N_ + n;
    for (int c = 0; c < C_; ++c) o[(size_t)c * N_] = f2b((b2f(p[(size_t)c * N_]) - mu) * rs * gam[c] + bet[c]);
}

// ---------------- K11: fc1 GEMM + gelu -> h1 (bf16) ----------------
__global__ __launch_bounds__(256) void k_fc1(const bf16* __restrict__ xn, const float* __restrict__ w1,
                                             const float* __restrict__ b1, bf16* __restrict__ h1) {
    __shared__ __align__(16) float a_lds[128][64];
    __shared__ __align__(16) float w_lds[16][256];
    int tid = threadIdx.x;
    int gtok = blockIdx.x * 64; int b = gtok >> 14; int nb = gtok & (N_ - 1);
    const bf16* A = xn + (size_t)b * C_ * N_ + nb;
    for (int e = tid; e < 8192; e += 256) { int c = e >> 6, i = e & 63; a_lds[c][i] = b2f(A[(size_t)c * N_ + i]); }
    int tn = tid & 15, to = tid >> 4;
    float acc[4][16] = {};
    for (int c0 = 0; c0 < 128; c0 += 16) {
        __syncthreads();
        for (int e = tid; e < 4096; e += 256) { int cc = e >> 8, o = e & 255; w_lds[cc][o] = w1[(c0 + cc) * 256 + o]; }
        __syncthreads();
        for (int cc = 0; cc < 16; ++cc) {
            float4 a4 = *(const float4*)&a_lds[c0 + cc][tn * 4];
            const float4* wr4 = (const float4*)&w_lds[cc][to * 16];
            float4 w0 = wr4[0], w1v = wr4[1], w2 = wr4[2], w3 = wr4[3];
            float wv[16] = {w0.x, w0.y, w0.z, w0.w, w1v.x, w1v.y, w1v.z, w1v.w,
                            w2.x, w2.y, w2.z, w2.w, w3.x, w3.y, w3.z, w3.w};
            #pragma unroll
            for (int oj = 0; oj < 16; ++oj) {
                float wvv = wv[oj];
                acc[0][oj] += a4.x * wvv; acc[1][oj] += a4.y * wvv;
                acc[2][oj] += a4.z * wvv; acc[3][oj] += a4.w * wvv;
            }
        }
    }
    #pragma unroll
    for (int rr = 0; rr < 4; ++rr) {
        int n = nb + tn * 4 + rr;
        #pragma unroll
        for (int oj = 0; oj < 16; ++oj) {
            int o = to * 16 + oj;
            h1[(size_t)(b * 256 + o) * N_ + n] = f2b(gelu_f(acc[rr][oj] + b1[o]));
        }
    }
}

// ---------------- K12: h2 = h1 + dwconv5x5(h1) + dw_b (bf16) ----------------
__global__ __launch_bounds__(256) void k_dw5(const bf16* __restrict__ h1, const float* __restrict__ wdw,
                                             const float* __restrict__ bdw, bf16* __restrict__ h2) {
    int idx = blockIdx.x * 256 + threadIdx.x;      // 33,554,432
    int w = idx & 127, h = (idx >> 7) & 127, ch = (idx >> 14) & 255, b = idx >> 22;
    const bf16* p = h1 + (size_t)(b * 256 + ch) * N_;
    const float* kw = wdw + ch * 25;
    float s = 0.f;
    #pragma unroll
    for (int ky = 0; ky < 5; ++ky) {
        int hh = h + ky - 2;
        if ((unsigned)hh >= 128u) continue;
        #pragma unroll
        for (int kx = 0; kx < 5; ++kx) {
            int ww = w + kx - 2;
            if ((unsigned)ww >= 128u) continue;
            s += kw[ky * 5 + kx] * b2f(p[hh * W_ + ww]);
        }
    }
    h2[idx] = f2b(b2f(p[h * W_ + w]) + s + bdw[ch]);
}

// ---------------- K13: fc2 GEMM + bias + residual -> d_out (fp32) ----------------
__global__ __launch_bounds__(256) void k_fc2(const bf16* __restrict__ h2, const float* __restrict__ w2,
                                             const float* __restrict__ b2, const bf16* __restrict__ x2,
                                             float* __restrict__ out) {
    __shared__ __align__(16) float a_lds[256][64];
    __shared__ __align__(16) float w_lds[16][128];
    int tid = threadIdx.x;
    int gtok = blockIdx.x * 64; int b = gtok >> 14; int nb = gtok & (N_ - 1);
    const bf16* A = h2 + (size_t)b * 256 * N_ + nb;
    for (int e = tid; e < 16384; e += 256) { int c = e >> 6, i = e & 63; a_lds[c][i] = b2f(A[(size_t)c * N_ + i]); }
    int tn = tid & 15, to = tid >> 4;
    float acc[4][8] = {};
    for (int c0 = 0; c0 < 256; c0 += 16) {
        __syncthreads();
        for (int e = tid; e < 2048; e += 256) { int cc = e >> 7, o = e & 127; w_lds[cc][o] = w2[(c0 + cc) * 128 + o]; }
        __syncthreads();
        for (int cc = 0; cc < 16; ++cc) {
            float4 a4 = *(const float4*)&a_lds[c0 + cc][tn * 4];
            const float4* wr4 = (const float4*)&w_lds[cc][to * 8];
            float4 wa = wr4[0], wb = wr4[1];
            float wv[8] = {wa.x, wa.y, wa.z, wa.w, wb.x, wb.y, wb.z, wb.w};
            #pragma unroll
            for (int oj = 0; oj < 8; ++oj) {
                float wvv = wv[oj];
                acc[0][oj] += a4.x * wvv; acc[1][oj] += a4.y * wvv;
                acc[2][oj] += a4.z * wvv; acc[3][oj] += a4.w * wvv;
            }
        }
    }
    #pragma unroll
    for (int rr = 0; rr < 4; ++rr) {
        int n = nb + tn * 4 + rr;
        #pragma unroll
        for (int oj = 0; oj < 8; ++oj) {
            int o = to * 8 + oj;
            size_t addr = (size_t)(b * C_ + o) * N_ + n;
            out[addr] = acc[rr][oj] + b2[o] + b2f(x2[addr]);
        }
    }
}

extern "C" void kernel_launch(void* const* d_in, const int* in_sizes, int n_in,
                              void* d_out, int out_size, void* d_ws, size_t ws_size,
                              hipStream_t stream) {
    const float* x         = (const float*)d_in[0];
    const float* lth_dw_w  = (const float*)d_in[2];
    const float* lth_pw_w  = (const float*)d_in[3];
    const float* lth_pw_b  = (const float*)d_in[4];
    const float* lth_gate_w= (const float*)d_in[5];
    const float* lth_gate_b= (const float*)d_in[6];
    const float* lth_scale = (const float*)d_in[7];
    const float* ln1_g     = (const float*)d_in[8];
    const float* ln1_b     = (const float*)d_in[9];
    const float* ln2_g     = (const float*)d_in[10];
    const float* ln2_b     = (const float*)d_in[11];
    const float* qkv_w     = (const float*)d_in[12];
    const float* gate_w    = (const float*)d_in[13];
    const float* gate_b    = (const float*)d_in[14];
    const float* proj_w    = (const float*)d_in[15];
    const float* pe_w      = (const float*)d_in[16];
    const float* pe_b      = (const float*)d_in[17];
    const float* fc1_w     = (const float*)d_in[18];
    const float* fc1_b     = (const float*)d_in[19];
    const float* dw_w      = (const float*)d_in[20];
    const float* dw_b      = (const float*)d_in[21];
    const float* fc2_w     = (const float*)d_in[22];
    const float* fc2_b     = (const float*)d_in[23];

    // Slab plan (bytes), peak 194 MiB (proven):
    //  A @0      (32 MiB)  : x1 -> xn ; h2 spans A+B
    //  B @A+32M  (40.5 MiB): low+sg -> o
    //  C @B+40.5 (40.5 MiB): q -> x2
    //  D @C+40.5 (40.5 MiB): hf -> k -> t2 ; h1 spans D+E
    //  E @D+40.5 (40.5 MiB): g -> v -> z
    char* ws = (char*)d_ws;
    constexpr size_t SZ_X = 33554432;    // bf16, 16,777,216 elems
    constexpr size_t SZ_W = 42467328;    // bf16, 21,233,664 elems
    constexpr size_t OFF_A = 0;
    constexpr size_t OFF_B = OFF_A + SZ_X;
    constexpr size_t OFF_C = OFF_B + SZ_W;
    constexpr size_t OFF_D = OFF_C + SZ_W;
    constexpr size_t OFF_E = OFF_D + SZ_W;

    bf16*  x1  = (bf16*)(ws + OFF_A);
    bf16*  xn  = (bf16*)(ws + OFF_A);
    bf16*  h2  = (bf16*)(ws + OFF_A);   // spans A+B
    float* low = (float*)(ws + OFF_B);
    float* sg  = (float*)(ws + OFF_B + 16777216);
    bf16*  o   = (bf16*)(ws + OFF_B);
    bf16*  q   = (bf16*)(ws + OFF_C);
    bf16*  x2  = (bf16*)(ws + OFF_C);
    bf16*  hf  = (bf16*)(ws + OFF_D);
    bf16*  k   = (bf16*)(ws + OFF_D);
    bf16*  t2  = (bf16*)(ws + OFF_D);
    bf16*  h1  = (bf16*)(ws + OFF_D);   // spans D+E
    bf16*  g   = (bf16*)(ws + OFF_E);
    bf16*  v   = (bf16*)(ws + OFF_E);
    bf16*  z   = (bf16*)(ws + OFF_E);   // after v is consumed

    k_pool    <<<16384, 256, 0, stream>>>(x, low);
    k_hf      <<<65536, 256, 0, stream>>>(x, low, hf);
    k_sgate   <<<512,   256, 0, stream>>>(hf, lth_gate_w, lth_gate_b, sg);
    k_dw3     <<<65536, 256, 0, stream>>>(hf, lth_dw_w, g);
    k_pw      <<<2048,  256, 0, stream>>>(g, lth_pw_w, lth_pw_b, x, lth_scale, sg, x1);
    k_qkv     <<<2592,  256, 0, stream>>>(x1, ln1_g, ln1_b, qkv_w, q, k, v);
    k_attn_mfma<<<2592, 256, 0, stream>>>(q, k, v, o);
    k_zgate   <<<2592,  256, 0, stream>>>(x1, ln1_g, ln1_b, gate_w, gate_b, z);
    k_pe_proj <<<2592,  256, 0, stream>>>(o, q, z, x1, pe_w, pe_b, proj_w, t2);
    k_fold    <<<65536, 256, 0, stream>>>(t2, x2);
    k_ln2     <<<512,   256, 0, stream>>>(x2, ln2_g, ln2_b, xn);
    k_fc1     <<<2048,  256, 0, stream>>>(xn, fc1_w, fc1_b, h1);
    k_dw5     <<<131072,256, 0, stream>>>(h1, dw_w, dw_b, h2);
    k_fc2     <<<2048,  256, 0, stream>>>(h2, fc2_w, fc2_b, x2, (float*)d_out);
}

// Round 6
// 5825.452 us; speedup vs baseline: 3.7058x; 3.7058x over previous
//
#include <hip/hip_runtime.h>
#include <hip/hip_bf16.h>
#include <math.h>

typedef __hip_bfloat16 bf16;
typedef __attribute__((ext_vector_type(8))) short bf16x8;
typedef __attribute__((ext_vector_type(4))) float f32x4;

static constexpr int B_ = 8, C_ = 128, H_ = 128, W_ = 128;
static constexpr int N_ = H_ * W_;          // 16384
static constexpr int NWIN = 648;            // B * 9 * 9

__device__ __forceinline__ float b2f(bf16 v) { return __bfloat162float(v); }
__device__ __forceinline__ bf16 f2b(float v) { return __float2bfloat16(v); }

// erf-free exact-GELU: A&S 7.1.26 rational erf approx (|err|<=1.5e-7), pure FMA + v_exp.
// Avoids libm erff (suspected non-inlined ocml call -> scratch traffic; R2-R5 anomaly).
__device__ __forceinline__ float gelu_f(float x) {
    float xs = x * 0.70710678118654752f;
    float ax = fabsf(xs);
    float t = 1.0f / fmaf(0.3275911f, ax, 1.0f);
    float poly = t * fmaf(t, fmaf(t, fmaf(t, fmaf(t, 1.061405429f, -1.453152027f), 1.421413741f), -0.284496736f), 0.254829592f);
    float erf_ax = fmaf(-poly, __expf(-ax * ax), 1.0f);
    float erfv = copysignf(erf_ax, xs);
    return 0.5f * x * (1.0f + erfv);
}

// ---------------- K1: 2x2 avg pool (fp32) ----------------
__global__ __launch_bounds__(256) void k_pool(const float* __restrict__ x, float* __restrict__ low) {
    int idx = blockIdx.x * 256 + threadIdx.x;       // 4,194,304
    int j = idx & 63, i = (idx >> 6) & 63, bc = idx >> 12;
    const float* p = x + (size_t)bc * N_ + (i * 2) * W_ + j * 2;
    low[idx] = (p[0] + p[1] + p[W_] + p[W_ + 1]) * 0.25f;
}

// ---------------- K2: hf = x - bilinear_up(low)  (bf16 out) ----------------
__global__ __launch_bounds__(256) void k_hf(const float* __restrict__ x, const float* __restrict__ low,
                                            bf16* __restrict__ hf) {
    int idx = blockIdx.x * 256 + threadIdx.x;       // 16,777,216
    int w = idx & 127, h = (idx >> 7) & 127, bc = idx >> 14;
    int jh = h >> 1, jw = w >> 1;
    int h0, h1; float wh0, wh1;
    if (h & 1) { h0 = jh; h1 = jh + 1 > 63 ? 63 : jh + 1; wh0 = 0.75f; wh1 = 0.25f; }
    else       { h0 = jh - 1 < 0 ? 0 : jh - 1; h1 = jh;   wh0 = 0.25f; wh1 = 0.75f; }
    int w0, w1; float ww0, ww1;
    if (w & 1) { w0 = jw; w1 = jw + 1 > 63 ? 63 : jw + 1; ww0 = 0.75f; ww1 = 0.25f; }
    else       { w0 = jw - 1 < 0 ? 0 : jw - 1; w1 = jw;   ww0 = 0.25f; ww1 = 0.75f; }
    const float* lp = low + (size_t)bc * 4096;
    float up = wh0 * (ww0 * lp[h0 * 64 + w0] + ww1 * lp[h0 * 64 + w1])
             + wh1 * (ww0 * lp[h1 * 64 + w0] + ww1 * lp[h1 * 64 + w1]);
    hf[idx] = f2b(x[idx] - up);
}

// ---------------- K3: sgate (fp32 out) ----------------
__global__ __launch_bounds__(256) void k_sgate(const bf16* __restrict__ hf, const float* __restrict__ gw,
                                               const float* __restrict__ gb, float* __restrict__ sg) {
    int idx = blockIdx.x * 256 + threadIdx.x;       // 131072
    int n = idx & (N_ - 1); int b = idx >> 14;
    const bf16* p = hf + (size_t)b * C_ * N_ + n;
    float s = 0.f;
    for (int c = 0; c < C_; ++c) s += gw[c] * fabsf(b2f(p[(size_t)c * N_]));
    s += gb[0];
    sg[idx] = 1.0f / (1.0f + __expf(-s));
}

// ---------------- K4: g = gelu(dwconv3x3 dil2) (bf16) ----------------
__global__ __launch_bounds__(256) void k_dw3(const bf16* __restrict__ hf, const float* __restrict__ wdw,
                                             bf16* __restrict__ g) {
    int idx = blockIdx.x * 256 + threadIdx.x;
    int w = idx & 127, h = (idx >> 7) & 127, bc = idx >> 14, c = bc & 127;
    const bf16* p = hf + (size_t)bc * N_;
    const float* kw = wdw + c * 9;
    float s = 0.f;
    #pragma unroll
    for (int ky = 0; ky < 3; ++ky) {
        int hh = h + (ky - 1) * 2;
        if ((unsigned)hh >= 128u) continue;
        #pragma unroll
        for (int kx = 0; kx < 3; ++kx) {
            int ww = w + (kx - 1) * 2;
            if ((unsigned)ww >= 128u) continue;
            s += kw[ky * 3 + kx] * b2f(p[hh * W_ + ww]);
        }
    }
    g[idx] = f2b(gelu_f(s));
}

// ---------------- K5: pw GEMM + LTH epilogue -> x1 (bf16) ----------------
__global__ __launch_bounds__(256) void k_pw(const bf16* __restrict__ g, const float* __restrict__ pww,
                                            const float* __restrict__ pwb, const float* __restrict__ x,
                                            const float* __restrict__ scale, const float* __restrict__ sg,
                                            bf16* __restrict__ x1) {
    __shared__ __align__(16) float a_lds[128][64];
    __shared__ __align__(16) float w_lds[16][128];
    int tid = threadIdx.x;
    int gtok = blockIdx.x * 64; int b = gtok >> 14; int nb = gtok & (N_ - 1);
    const bf16* A = g + (size_t)b * C_ * N_ + nb;
    for (int e = tid; e < 8192; e += 256) { int c = e >> 6, i = e & 63; a_lds[c][i] = b2f(A[(size_t)c * N_ + i]); }
    int tn = tid & 15, to = tid >> 4;
    float acc[4][8] = {};
    for (int c0 = 0; c0 < 128; c0 += 16) {
        __syncthreads();
        for (int e = tid; e < 2048; e += 256) { int cc = e & 15, o = e >> 4; w_lds[cc][o] = pww[o * 128 + c0 + cc]; }
        __syncthreads();
        for (int cc = 0; cc < 16; ++cc) {
            float4 a4 = *(const float4*)&a_lds[c0 + cc][tn * 4];
            const float4* wr4 = (const float4*)&w_lds[cc][to * 8];
            float4 wa = wr4[0], wb = wr4[1];
            float wv[8] = {wa.x, wa.y, wa.z, wa.w, wb.x, wb.y, wb.z, wb.w};
            #pragma unroll
            for (int oj = 0; oj < 8; ++oj) {
                float wvv = wv[oj];
                acc[0][oj] += a4.x * wvv; acc[1][oj] += a4.y * wvv;
                acc[2][oj] += a4.z * wvv; acc[3][oj] += a4.w * wvv;
            }
        }
    }
    int nb4 = nb + tn * 4;
    float4 sg4 = *(const float4*)&sg[(b << 14) + nb4];
    #pragma unroll
    for (int oj = 0; oj < 8; ++oj) {
        int o = to * 8 + oj;
        size_t obase = (size_t)(b * C_ + o) * N_ + nb4;
        float4 x4 = *(const float4*)&x[obase];
        float sc = scale[o], bi = pwb[o];
        union { bf16 h[4]; uint2 u; } t4;
        t4.h[0] = f2b(x4.x + sc * (acc[0][oj] + bi) * sg4.x);
        t4.h[1] = f2b(x4.y + sc * (acc[1][oj] + bi) * sg4.y);
        t4.h[2] = f2b(x4.z + sc * (acc[2][oj] + bi) * sg4.z);
        t4.h[3] = f2b(x4.w + sc * (acc[3][oj] + bi) * sg4.w);
        *(uint2*)(x1 + obase) = t4.u;
    }
}

// ---------------- K6: fused LN1 + qkv+gate GEMM (4 passes) -> q,k [tok][c]; v,z [c][tok] ----------------
__global__ __launch_bounds__(256) void k_qkv(const bf16* __restrict__ x1, const float* __restrict__ lng,
                                             const float* __restrict__ lnb, const float* __restrict__ qkvw,
                                             const float* __restrict__ gatew, const float* __restrict__ gateb,
                                             bf16* __restrict__ q, bf16* __restrict__ k, bf16* __restrict__ v,
                                             bf16* __restrict__ z) {
    __shared__ __align__(16) float y_lds[128][64];
    __shared__ __align__(16) float w_lds[16][128];
    __shared__ float red2[8][64];
    __shared__ float mu_l[64], rs_l[64];
    int tid = threadIdx.x;
    int win = blockIdx.x >> 2; int tokbase = (blockIdx.x & 3) * 64;
    int b = win / 81; int r0 = win % 81; int top = (r0 / 9) * 14, left = (r0 % 9) * 14;
    for (int e = tid; e < 8192; e += 256) {
        int c = e >> 6, i = e & 63; int tok = tokbase + i; int p = tok >> 4, qq = tok & 15;
        y_lds[c][i] = b2f(x1[(size_t)(b * C_ + c) * N_ + (top + p) * W_ + (left + qq)]);
    }
    __syncthreads();
    { // LN stats: 4 partials per token
        int i = tid & 63, r = tid >> 6;
        float s = 0.f, ss = 0.f;
        for (int cc = r * 32; cc < r * 32 + 32; ++cc) { float vv = y_lds[cc][i]; s += vv; ss += vv * vv; }
        red2[r][i] = s; red2[4 + r][i] = ss;
    }
    __syncthreads();
    if (tid < 64) {
        float s = red2[0][tid] + red2[1][tid] + red2[2][tid] + red2[3][tid];
        float ss = red2[4][tid] + red2[5][tid] + red2[6][tid] + red2[7][tid];
        float mu = s * (1.f / 128.f); float var = ss * (1.f / 128.f) - mu * mu;
        mu_l[tid] = mu; rs_l[tid] = rsqrtf(var + 1e-6f);
    }
    __syncthreads();
    for (int e = tid; e < 8192; e += 256) {
        int c = e >> 6, i = e & 63;
        y_lds[c][i] = (y_lds[c][i] - mu_l[i]) * rs_l[i] * lng[c] + lnb[c];
    }
    int tn = tid & 15, to = tid >> 4;
    for (int pass = 0; pass < 4; ++pass) {
        float acc[4][8] = {};
        for (int c0 = 0; c0 < 128; c0 += 16) {
            __syncthreads();
            for (int e = tid; e < 2048; e += 256) {
                int cc = e >> 7, o = e & 127;
                w_lds[cc][o] = (pass < 3) ? qkvw[(c0 + cc) * 384 + pass * 128 + o]
                                          : gatew[(c0 + cc) * 128 + o];
            }
            __syncthreads();
            for (int cc = 0; cc < 16; ++cc) {
                float4 a4 = *(const float4*)&y_lds[c0 + cc][tn * 4];
                const float4* wr4 = (const float4*)&w_lds[cc][to * 8];
                float4 wa = wr4[0], wb = wr4[1];
                float wv[8] = {wa.x, wa.y, wa.z, wa.w, wb.x, wb.y, wb.z, wb.w};
                #pragma unroll
                for (int oj = 0; oj < 8; ++oj) {
                    float wvv = wv[oj];
                    acc[0][oj] += a4.x * wvv; acc[1][oj] += a4.y * wvv;
                    acc[2][oj] += a4.z * wvv; acc[3][oj] += a4.w * wvv;
                }
            }
        }
        if (pass < 2) {
            bf16* outp = (pass == 0) ? q : k;      // [win][tok][c]
            #pragma unroll
            for (int rr = 0; rr < 4; ++rr) {
                int tok = tokbase + tn * 4 + rr;
                union { bf16 h[8]; uint4 u; } tmp;
                #pragma unroll
                for (int oj = 0; oj < 8; ++oj) tmp.h[oj] = f2b(acc[rr][oj]);
                *(uint4*)(outp + ((size_t)win * 256 + tok) * 128 + to * 8) = tmp.u;
            }
        } else if (pass == 2) {                    // v: [win][c][tok], packed along tok
            #pragma unroll
            for (int oj = 0; oj < 8; ++oj) {
                int o = to * 8 + oj;
                union { bf16 h[4]; uint2 u; } t4;
                #pragma unroll
                for (int rr = 0; rr < 4; ++rr) t4.h[rr] = f2b(acc[rr][oj]);
                *(uint2*)(v + (size_t)win * 32768 + (size_t)o * 256 + tokbase + tn * 4) = t4.u;
            }
        } else {                                    // z: [win][c][tok], gelu(acc+gateb)
            #pragma unroll
            for (int oj = 0; oj < 8; ++oj) {
                int o = to * 8 + oj;
                float gb = gateb[o];
                union { bf16 h[4]; uint2 u; } t4;
                #pragma unroll
                for (int rr = 0; rr < 4; ++rr) t4.h[rr] = f2b(gelu_f(acc[rr][oj] + gb));
                *(uint2*)(z + (size_t)win * 32768 + (size_t)o * 256 + tokbase + tn * 4) = t4.u;
            }
        }
        __syncthreads();
    }
}

// ---------------- K7: MFMA attention core: softmax(QK^T*scale)V -> o [win][tok][c] ----------------
__global__ __launch_bounds__(256) void k_attn_mfma(const bf16* __restrict__ qb, const bf16* __restrict__ kb,
                                                   const bf16* __restrict__ vb, bf16* __restrict__ ob) {
    __shared__ __align__(16) char lds[49152];   // [0,32K): q (16K) then P (32K); [32K,48K): K/V chunk
    int tid = threadIdx.x;
    int lane = tid & 63, w = tid >> 6;
    int l15 = lane & 15, lhi = lane >> 4;
    int win = blockIdx.x >> 2, qbase = (blockIdx.x & 3) * 64;
    const bf16* qg = qb + ((size_t)win * 256 + qbase) * 128;   // [64][128]
    const bf16* kg = kb + (size_t)win * 256 * 128;             // [256][128]
    const bf16* vg = vb + (size_t)win * 128 * 256;             // [128][256]
    char* chunk = lds + 32768;
    for (int e = tid; e < 1024; e += 256) {
        int row = e >> 4, slot = e & 15;
        uint4 val = *(const uint4*)((const char*)qg + row * 256 + slot * 16);
        *(uint4*)(lds + row * 256 + ((slot * 16) ^ ((row & 7) << 4))) = val;
    }
    __syncthreads();
    bf16x8 afr[4];
    {
        int row = w * 16 + l15;
        #pragma unroll
        for (int cc = 0; cc < 4; ++cc) {
            int cb = cc * 64 + lhi * 16;
            afr[cc] = *(const bf16x8*)(lds + row * 256 + (cb ^ ((row & 7) << 4)));
        }
    }
    f32x4 acc[16];
    #pragma unroll
    for (int t = 0; t < 16; ++t) acc[t] = (f32x4){0.f, 0.f, 0.f, 0.f};
    for (int kc = 0; kc < 4; ++kc) {
        __syncthreads();
        for (int e = tid; e < 1024; e += 256) {
            int row = e >> 4, slot = e & 15;
            uint4 val = *(const uint4*)((const char*)kg + (size_t)(kc * 64 + row) * 256 + slot * 16);
            *(uint4*)(chunk + row * 256 + ((slot * 16) ^ ((row & 7) << 4))) = val;
        }
        __syncthreads();
        #pragma unroll
        for (int t = 0; t < 4; ++t) {
            int row = t * 16 + l15;
            #pragma unroll
            for (int cc = 0; cc < 4; ++cc) {
                int cb = cc * 64 + lhi * 16;
                bf16x8 bfr = *(const bf16x8*)(chunk + row * 256 + (cb ^ ((row & 7) << 4)));
                acc[kc * 4 + t] = __builtin_amdgcn_mfma_f32_16x16x32_bf16(afr[cc], bfr, acc[kc * 4 + t], 0, 0, 0);
            }
        }
    }
    const float sm_scale = 0.08838834764831845f;   // 128^-0.5
    #pragma unroll
    for (int r = 0; r < 4; ++r) {
        float m = -1e30f;
        #pragma unroll
        for (int t = 0; t < 16; ++t) m = fmaxf(m, acc[t][r]);
        #pragma unroll
        for (int d2 = 1; d2 < 16; d2 <<= 1) m = fmaxf(m, __shfl_xor(m, d2, 64));
        float ssum = 0.f;
        #pragma unroll
        for (int t = 0; t < 16; ++t) { float p = __expf((acc[t][r] - m) * sm_scale); acc[t][r] = p; ssum += p; }
        #pragma unroll
        for (int d2 = 1; d2 < 16; d2 <<= 1) ssum += __shfl_xor(ssum, d2, 64);
        float inv = 1.f / ssum;
        #pragma unroll
        for (int t = 0; t < 16; ++t) acc[t][r] *= inv;
    }
    #pragma unroll
    for (int t = 0; t < 16; ++t) {
        #pragma unroll
        for (int r = 0; r < 4; ++r) {
            int row = w * 16 + lhi * 4 + r;
            int cb = (t * 16 + l15) * 2;
            *(bf16*)(lds + row * 512 + (cb ^ ((row & 7) << 4))) = f2b(acc[t][r]);
        }
    }
    f32x4 oacc[8];
    #pragma unroll
    for (int t = 0; t < 8; ++t) oacc[t] = (f32x4){0.f, 0.f, 0.f, 0.f};
    for (int vc = 0; vc < 4; ++vc) {
        __syncthreads();
        for (int e = tid; e < 1024; e += 256) {
            int row = e >> 3, slot = e & 7;
            uint4 val = *(const uint4*)((const char*)vg + (size_t)row * 512 + vc * 128 + slot * 16);
            *(uint4*)(chunk + row * 128 + ((slot * 16) ^ ((row & 7) << 4))) = val;
        }
        __syncthreads();
        #pragma unroll
        for (int jc = 0; jc < 2; ++jc) {
            int prow = w * 16 + l15;
            int pcb = vc * 128 + jc * 64 + lhi * 16;
            bf16x8 ap = *(const bf16x8*)(lds + prow * 512 + (pcb ^ ((prow & 7) << 4)));
            #pragma unroll
            for (int ct = 0; ct < 8; ++ct) {
                int vrow = ct * 16 + l15;
                int vcb = jc * 64 + lhi * 16;
                bf16x8 bv = *(const bf16x8*)(chunk + vrow * 128 + (vcb ^ ((vrow & 7) << 4)));
                oacc[ct] = __builtin_amdgcn_mfma_f32_16x16x32_bf16(ap, bv, oacc[ct], 0, 0, 0);
            }
        }
    }
    bf16* og = ob + ((size_t)win * 256 + qbase) * 128;
    #pragma unroll
    for (int ct = 0; ct < 8; ++ct) {
        #pragma unroll
        for (int r = 0; r < 4; ++r) {
            int row = w * 16 + lhi * 4 + r;
            og[row * 128 + ct * 16 + l15] = f2b(oacc[ct][r]);
        }
    }
}

// ---------------- K8: PE + gate-mul + proj GEMM + crop residual -> t2 [win][c][tok] (bf16) ----------------
__global__ __launch_bounds__(256) void k_pe_proj(const bf16* __restrict__ ob, const bf16* __restrict__ qb,
                                                 const bf16* __restrict__ zb, const bf16* __restrict__ x1,
                                                 const float* __restrict__ pew, const float* __restrict__ peb,
                                                 const float* __restrict__ projw, bf16* __restrict__ t2) {
    __shared__ __align__(16) float y_lds[128][64];     // gated A for proj
    __shared__ __align__(16) float w_lds[16][128];
    __shared__ __align__(16) bf16 xt_lds[128][64];     // raw crop (residual)
    int tid = threadIdx.x;
    int win = blockIdx.x >> 2; int qbase = (blockIdx.x & 3) * 64;
    int b = win / 81; int r0 = win % 81; int top = (r0 / 9) * 14, left = (r0 % 9) * 14;
    for (int e = tid; e < 8192; e += 256) {
        int c = e >> 6, i = e & 63; int tok = qbase + i; int p = tok >> 4, qq = tok & 15;
        xt_lds[c][i] = x1[(size_t)(b * C_ + c) * N_ + (top + p) * W_ + (left + qq)];
    }
    // ---- PE + gate -> y_lds[c][tok], 4 sub-phases x 8 channels/thread ----
    {
        int tok = tid & 63, cg = tid >> 6;
        int gtok = qbase + tok; int pp = gtok >> 4, qq = gtok & 15;
        #pragma unroll 1
        for (int sub = 0; sub < 4; ++sub) {
            int cb = cg * 8 + sub * 32;
            float pv[8];
            #pragma unroll
            for (int cc = 0; cc < 8; ++cc) pv[cc] = peb[cb + cc];
            #pragma unroll
            for (int ky = 0; ky < 3; ++ky) {
                int py = pp + ky - 1; if ((unsigned)py >= 16u) continue;
                #pragma unroll
                for (int kx = 0; kx < 3; ++kx) {
                    int qx = qq + kx - 1; if ((unsigned)qx >= 16u) continue;
                    union { uint4 u; bf16 h[8]; } qu;
                    qu.u = *(const uint4*)(qb + ((size_t)win * 256 + py * 16 + qx) * 128 + cb);
                    #pragma unroll
                    for (int cc = 0; cc < 8; ++cc)
                        pv[cc] += pew[(cb + cc) * 9 + ky * 3 + kx] * b2f(qu.h[cc]);
                }
            }
            union { uint4 u; bf16 h[8]; } ou;
            ou.u = *(const uint4*)(ob + ((size_t)win * 256 + gtok) * 128 + cb);
            #pragma unroll
            for (int cc = 0; cc < 8; ++cc) {
                int c = cb + cc;
                float zval = b2f(zb[(size_t)win * 32768 + (size_t)c * 256 + gtok]);
                y_lds[c][tok] = (b2f(ou.h[cc]) + pv[cc]) * zval;
            }
        }
    }
    int tn = tid & 15, to = tid >> 4;
    // ---- proj GEMM + crop residual -> t2 ----
    float pacc[4][8] = {};
    for (int c0 = 0; c0 < 128; c0 += 16) {
        __syncthreads();
        for (int e = tid; e < 2048; e += 256) { int cc = e >> 7, o = e & 127; w_lds[cc][o] = projw[(c0 + cc) * 128 + o]; }
        __syncthreads();
        for (int cc = 0; cc < 16; ++cc) {
            float4 a4 = *(const float4*)&y_lds[c0 + cc][tn * 4];
            const float4* wr4 = (const float4*)&w_lds[cc][to * 8];
            float4 wa = wr4[0], wb = wr4[1];
            float wv[8] = {wa.x, wa.y, wa.z, wa.w, wb.x, wb.y, wb.z, wb.w};
            #pragma unroll
            for (int oj = 0; oj < 8; ++oj) {
                float wvv = wv[oj];
                pacc[0][oj] += a4.x * wvv; pacc[1][oj] += a4.y * wvv;
                pacc[2][oj] += a4.z * wvv; pacc[3][oj] += a4.w * wvv;
            }
        }
    }
    #pragma unroll
    for (int oj = 0; oj < 8; ++oj) {
        int o = to * 8 + oj;
        union { bf16 h[4]; uint2 u; } t4;
        #pragma unroll
        for (int rr = 0; rr < 4; ++rr)
            t4.h[rr] = f2b(pacc[rr][oj] + b2f(xt_lds[o][tn * 4 + rr]));
        *(uint2*)(t2 + (size_t)win * 32768 + (size_t)o * 256 + qbase + tn * 4) = t4.u;
    }
}

// ---------------- K9: overlap-fold with divisor -> x2 (bf16) ----------------
__global__ __launch_bounds__(256) void k_fold(const bf16* __restrict__ t2, bf16* __restrict__ x2) {
    int idx = blockIdx.x * 256 + threadIdx.x;      // 16,777,216
    int w = idx & 127, h = (idx >> 7) & 127, c = (idx >> 14) & 127, b = idx >> 21;
    int imin = (h < 16) ? 0 : (h - 2) / 14; int imax = h / 14; if (imax > 8) imax = 8;
    int jmin = (w < 16) ? 0 : (w - 2) / 14; int jmax = w / 14; if (jmax > 8) jmax = 8;
    float sum = 0.f;
    for (int i = imin; i <= imax; ++i)
        for (int j = jmin; j <= jmax; ++j) {
            int win = (b * 9 + i) * 9 + j;
            sum += b2f(t2[(size_t)win * 32768 + c * 256 + (h - i * 14) * 16 + (w - j * 14)]);
        }
    int cnt = (imax - imin + 1) * (jmax - jmin + 1);
    x2[idx] = f2b(sum / (float)cnt);
}

// ---------------- K10: LN2 -> xn (bf16) ----------------
__global__ __launch_bounds__(256) void k_ln2(const bf16* __restrict__ x2, const float* __restrict__ gam,
                                             const float* __restrict__ bet, bf16* __restrict__ xn) {
    int idx = blockIdx.x * 256 + threadIdx.x;      // 131072
    int n = idx & (N_ - 1); int b = idx >> 14;
    const bf16* p = x2 + (size_t)b * C_ * N_ + n;
    float s = 0.f, ss = 0.f;
    for (int c = 0; c < C_; ++c) { float v = b2f(p[(size_t)c * N_]); s += v; ss += v * v; }
    float mu = s * (1.f / 128.f);
    float var = ss * (1.f / 128.f) - mu * mu;
    float rs = rsqrtf(var + 1e-6f);
    bf16* o = xn + (size_t)b * C_ * N_ + n;
    for (int c = 0; c < C_; ++c) o[(size_t)c * N_] = f2b((b2f(p[(size_t)c * N_]) - mu) * rs * gam[c] + bet[c]);
}

// ---------------- K11: fc1 GEMM + gelu -> h1 (bf16) ----------------
__global__ __launch_bounds__(256) void k_fc1(const bf16* __restrict__ xn, const float* __restrict__ w1,
                                             const float* __restrict__ b1, bf16* __restrict__ h1) {
    __shared__ __align__(16) float a_lds[128][64];
    __shared__ __align__(16) float w_lds[16][256];
    int tid = threadIdx.x;
    int gtok = blockIdx.x * 64; int b = gtok >> 14; int nb = gtok & (N_ - 1);
    const bf16* A = xn + (size_t)b * C_ * N_ + nb;
    for (int e = tid; e < 8192; e += 256) { int c = e >> 6, i = e & 63; a_lds[c][i] = b2f(A[(size_t)c * N_ + i]); }
    int tn = tid & 15, to = tid >> 4;
    float acc[4][16] = {};
    for (int c0 = 0; c0 < 128; c0 += 16) {
        __syncthreads();
        for (int e = tid; e < 4096; e += 256) { int cc = e >> 8, o = e & 255; w_lds[cc][o] = w1[(c0 + cc) * 256 + o]; }
        __syncthreads();
        for (int cc = 0; cc < 16; ++cc) {
            float4 a4 = *(const float4*)&a_lds[c0 + cc][tn * 4];
            const float4* wr4 = (const float4*)&w_lds[cc][to * 16];
            float4 w0 = wr4[0], w1v = wr4[1], w2 = wr4[2], w3 = wr4[3];
            float wv[16] = {w0.x, w0.y, w0.z, w0.w, w1v.x, w1v.y, w1v.z, w1v.w,
                            w2.x, w2.y, w2.z, w2.w, w3.x, w3.y, w3.z, w3.w};
            #pragma unroll
            for (int oj = 0; oj < 16; ++oj) {
                float wvv = wv[oj];
                acc[0][oj] += a4.x * wvv; acc[1][oj] += a4.y * wvv;
                acc[2][oj] += a4.z * wvv; acc[3][oj] += a4.w * wvv;
            }
        }
    }
    #pragma unroll
    for (int oj = 0; oj < 16; ++oj) {
        int o = to * 16 + oj;
        float bi = b1[o];
        union { bf16 h[4]; uint2 u; } t4;
        #pragma unroll
        for (int rr = 0; rr < 4; ++rr) t4.h[rr] = f2b(gelu_f(acc[rr][oj] + bi));
        *(uint2*)(h1 + (size_t)(b * 256 + o) * N_ + nb + tn * 4) = t4.u;
    }
}

// ---------------- K12: h2 = h1 + dwconv5x5(h1) + dw_b (bf16) ----------------
__global__ __launch_bounds__(256) void k_dw5(const bf16* __restrict__ h1, const float* __restrict__ wdw,
                                             const float* __restrict__ bdw, bf16* __restrict__ h2) {
    int idx = blockIdx.x * 256 + threadIdx.x;      // 33,554,432
    int w = idx & 127, h = (idx >> 7) & 127, ch = (idx >> 14) & 255, b = idx >> 22;
    const bf16* p = h1 + (size_t)(b * 256 + ch) * N_;
    const float* kw = wdw + ch * 25;
    float s = 0.f;
    #pragma unroll
    for (int ky = 0; ky < 5; ++ky) {
        int hh = h + ky - 2;
        if ((unsigned)hh >= 128u) continue;
        #pragma unroll
        for (int kx = 0; kx < 5; ++kx) {
            int ww = w + kx - 2;
            if ((unsigned)ww >= 128u) continue;
            s += kw[ky * 5 + kx] * b2f(p[hh * W_ + ww]);
        }
    }
    h2[idx] = f2b(b2f(p[h * W_ + w]) + s + bdw[ch]);
}

// ---------------- K13: fc2 GEMM + bias + residual -> d_out (fp32) ----------------
__global__ __launch_bounds__(256) void k_fc2(const bf16* __restrict__ h2, const float* __restrict__ w2,
                                             const float* __restrict__ b2, const bf16* __restrict__ x2,
                                             float* __restrict__ out) {
    __shared__ __align__(16) float a_lds[256][64];
    __shared__ __align__(16) float w_lds[16][128];
    int tid = threadIdx.x;
    int gtok = blockIdx.x * 64; int b = gtok >> 14; int nb = gtok & (N_ - 1);
    const bf16* A = h2 + (size_t)b * 256 * N_ + nb;
    for (int e = tid; e < 16384; e += 256) { int c = e >> 6, i = e & 63; a_lds[c][i] = b2f(A[(size_t)c * N_ + i]); }
    int tn = tid & 15, to = tid >> 4;
    float acc[4][8] = {};
    for (int c0 = 0; c0 < 256; c0 += 16) {
        __syncthreads();
        for (int e = tid; e < 2048; e += 256) { int cc = e >> 7, o = e & 127; w_lds[cc][o] = w2[(c0 + cc) * 128 + o]; }
        __syncthreads();
        for (int cc = 0; cc < 16; ++cc) {
            float4 a4 = *(const float4*)&a_lds[c0 + cc][tn * 4];
            const float4* wr4 = (const float4*)&w_lds[cc][to * 8];
            float4 wa = wr4[0], wb = wr4[1];
            float wv[8] = {wa.x, wa.y, wa.z, wa.w, wb.x, wb.y, wb.z, wb.w};
            #pragma unroll
            for (int oj = 0; oj < 8; ++oj) {
                float wvv = wv[oj];
                acc[0][oj] += a4.x * wvv; acc[1][oj] += a4.y * wvv;
                acc[2][oj] += a4.z * wvv; acc[3][oj] += a4.w * wvv;
            }
        }
    }
    #pragma unroll
    for (int oj = 0; oj < 8; ++oj) {
        int o = to * 8 + oj;
        size_t obase = (size_t)(b * C_ + o) * N_ + nb + tn * 4;
        float bi = b2[o];
        union { uint2 u; bf16 h[4]; } xr;
        xr.u = *(const uint2*)(x2 + obase);
        float4 r4;
        r4.x = acc[0][oj] + bi + b2f(xr.h[0]);
        r4.y = acc[1][oj] + bi + b2f(xr.h[1]);
        r4.z = acc[2][oj] + bi + b2f(xr.h[2]);
        r4.w = acc[3][oj] + bi + b2f(xr.h[3]);
        *(float4*)(out + obase) = r4;
    }
}

extern "C" void kernel_launch(void* const* d_in, const int* in_sizes, int n_in,
                              void* d_out, int out_size, void* d_ws, size_t ws_size,
                              hipStream_t stream) {
    const float* x         = (const float*)d_in[0];
    const float* lth_dw_w  = (const float*)d_in[2];
    const float* lth_pw_w  = (const float*)d_in[3];
    const float* lth_pw_b  = (const float*)d_in[4];
    const float* lth_gate_w= (const float*)d_in[5];
    const float* lth_gate_b= (const float*)d_in[6];
    const float* lth_scale = (const float*)d_in[7];
    const float* ln1_g     = (const float*)d_in[8];
    const float* ln1_b     = (const float*)d_in[9];
    const float* ln2_g     = (const float*)d_in[10];
    const float* ln2_b     = (const float*)d_in[11];
    const float* qkv_w     = (const float*)d_in[12];
    const float* gate_w    = (const float*)d_in[13];
    const float* gate_b    = (const float*)d_in[14];
    const float* proj_w    = (const float*)d_in[15];
    const float* pe_w      = (const float*)d_in[16];
    const float* pe_b      = (const float*)d_in[17];
    const float* fc1_w     = (const float*)d_in[18];
    const float* fc1_b     = (const float*)d_in[19];
    const float* dw_w      = (const float*)d_in[20];
    const float* dw_b      = (const float*)d_in[21];
    const float* fc2_w     = (const float*)d_in[22];
    const float* fc2_b     = (const float*)d_in[23];

    // Slab plan (bytes), peak 194 MiB (proven):
    //  A @0      (32 MiB)  : x1 -> xn ; h2 spans A+B
    //  B @A+32M  (40.5 MiB): low+sg -> o
    //  C @B+40.5 (40.5 MiB): q -> x2
    //  D @C+40.5 (40.5 MiB): hf -> k -> t2 ; h1 spans D+E
    //  E @D+40.5 (40.5 MiB): g -> v ; z in high half of D (k dead after attn)? No:
    //  z gets its own life: z shares E with v? v is read by attn AFTER qkv writes z...
    //  -> z must NOT overlap v. Put z in the low 40.5 MiB of... reuse low+sg region? o
    //     is written by attn AFTER qkv. o occupies all of B. So z lives in B until attn?
    //     No - attn writes o (B) while z must survive until pe_proj. Use D: k is read by
    //     attn, t2 written by pe_proj. z would clash with k (qkv writes both).
    //  Clean solution: shift: q->C, k->D, v->E, z->F (new 40.5 MiB slab, peak 234 MiB was
    //  too close to R1 failure? R1 failed at 533 MiB; 234 MiB likely fine given 194 worked).
    char* ws = (char*)d_ws;
    constexpr size_t SZ_X = 33554432;    // bf16, 16,777,216 elems
    constexpr size_t SZ_W = 42467328;    // bf16, 21,233,664 elems
    constexpr size_t OFF_A = 0;
    constexpr size_t OFF_B = OFF_A + SZ_X;
    constexpr size_t OFF_C = OFF_B + SZ_W;
    constexpr size_t OFF_D = OFF_C + SZ_W;
    constexpr size_t OFF_E = OFF_D + SZ_W;
    constexpr size_t OFF_F = OFF_E + SZ_W;   // peak 234 MiB

    bf16*  x1  = (bf16*)(ws + OFF_A);
    bf16*  xn  = (bf16*)(ws + OFF_A);
    bf16*  h2  = (bf16*)(ws + OFF_A);   // spans A+B
    float* low = (float*)(ws + OFF_B);
    float* sg  = (float*)(ws + OFF_B + 16777216);
    bf16*  o   = (bf16*)(ws + OFF_B);
    bf16*  q   = (bf16*)(ws + OFF_C);
    bf16*  x2  = (bf16*)(ws + OFF_C);
    bf16*  hf  = (bf16*)(ws + OFF_D);
    bf16*  k   = (bf16*)(ws + OFF_D);
    bf16*  t2  = (bf16*)(ws + OFF_D);
    bf16*  h1  = (bf16*)(ws + OFF_D);   // spans D+E
    bf16*  g   = (bf16*)(ws + OFF_E);
    bf16*  v   = (bf16*)(ws + OFF_E);
    bf16*  z   = (bf16*)(ws + OFF_F);

    k_pool    <<<16384, 256, 0, stream>>>(x, low);
    k_hf      <<<65536, 256, 0, stream>>>(x, low, hf);
    k_sgate   <<<512,   256, 0, stream>>>(hf, lth_gate_w, lth_gate_b, sg);
    k_dw3     <<<65536, 256, 0, stream>>>(hf, lth_dw_w, g);
    k_pw      <<<2048,  256, 0, stream>>>(g, lth_pw_w, lth_pw_b, x, lth_scale, sg, x1);
    k_qkv     <<<2592,  256, 0, stream>>>(x1, ln1_g, ln1_b, qkv_w, gate_w, gate_b, q, k, v, z);
    k_attn_mfma<<<2592, 256, 0, stream>>>(q, k, v, o);
    k_pe_proj <<<2592,  256, 0, stream>>>(o, q, z, x1, pe_w, pe_b, proj_w, t2);
    k_fold    <<<65536, 256, 0, stream>>>(t2, x2);
    k_ln2     <<<512,   256, 0, stream>>>(x2, ln2_g, ln2_b, xn);
    k_fc1     <<<2048,  256, 0, stream>>>(xn, fc1_w, fc1_b, h1);
    k_dw5     <<<131072,256, 0, stream>>>(h1, dw_w, dw_b, h2);
    k_fc2     <<<2048,  256, 0, stream>>>(h2, fc2_w, fc2_b, x2, (float*)d_out);
}